// Round 1
// baseline (766.386 us; speedup 1.0000x reference)
//
#include <hip/hip_runtime.h>
#include <hip/hip_bf16.h>

#define DIN 128
#define DHID 128
#define DCLS 64
#define BN_EPS 1e-5f
#define GEN_EPS 1e-7f

typedef __attribute__((ext_vector_type(8))) short short8;
typedef __attribute__((ext_vector_type(4))) float f32x4;

static __device__ __forceinline__ float bf2f(unsigned short u) {
    union { float f; unsigned int i; } x; x.i = ((unsigned int)u) << 16; return x.f;
}
static __device__ __forceinline__ unsigned short f2bf(float f) {
    union { float f; unsigned int i; } x; x.f = f;
    unsigned int r = x.i + 0x7fffu + ((x.i >> 16) & 1u);
    return (unsigned short)(r >> 16);
}

// ---------------- CSR build ----------------
__global__ void k_hist(const int* __restrict__ dst, int* __restrict__ counts, int E) {
    int e = blockIdx.x * 256 + threadIdx.x;
    if (e < E) atomicAdd(&counts[dst[e]], 1);
}

__global__ __launch_bounds__(1024) void k_scan(const int* __restrict__ counts,
        int* __restrict__ roff, int* __restrict__ cursor, float* __restrict__ dinv, int N) {
    __shared__ int lsum[1024];
    int t = threadIdx.x;
    int chunk = (N + 1023) >> 10;
    int b = t * chunk;
    int e = b + chunk; if (e > N) e = N;
    int s = 0;
    for (int i = b; i < e && i < N; i++) s += counts[i];
    lsum[t] = s;
    __syncthreads();
    for (int off = 1; off < 1024; off <<= 1) {
        int add = (t >= off) ? lsum[t - off] : 0;
        __syncthreads();
        lsum[t] += add;
        __syncthreads();
    }
    int run = (t == 0) ? 0 : lsum[t - 1];
    for (int i = b; i < e && i < N; i++) {
        roff[i] = run; cursor[i] = run;
        run += counts[i];
        dinv[i] = rsqrtf((float)(counts[i] + 1));
    }
    if (t == 1023) roff[N] = run;
}

__global__ void k_fill(const int* __restrict__ src, const int* __restrict__ dst,
        int* __restrict__ cursor, int* __restrict__ srcs, int E) {
    int e = blockIdx.x * 256 + threadIdx.x;
    if (e < E) {
        int d = dst[e];
        int p = atomicAdd(&cursor[d], 1);
        srcs[p] = src[e];
    }
}

// ---------------- weight transpose to bf16: Wt[n][k] = W[k][n] ----------------
__global__ void k_wt(const float* __restrict__ W, unsigned short* __restrict__ Wt, int K, int Dout) {
    int i = blockIdx.x * 256 + threadIdx.x;
    if (i >= K * Dout) return;
    int n = i / K, k = i - n * K;
    Wt[i] = f2bf(W[(size_t)k * Dout + n]);
}

// ---------------- GEMM: C[nrows,Dout] = op(A)[nrows,K] @ W[K,Dout] (+bias) ----------------
// op(A) = relu(A*scale+shift) if scale!=null.  Wt is bf16 row-major [Dout][K].
template<int K, bool ABF16, bool OBF16>
__global__ __launch_bounds__(256) void k_gemm(const void* __restrict__ Av,
        const unsigned short* __restrict__ Wt, const float* __restrict__ bias,
        const float* __restrict__ scale, const float* __restrict__ shift,
        void* __restrict__ Cv, int nrows, int Dout) {
    constexpr int KP = K + 8;
    __shared__ unsigned short sA[64 * KP];
    __shared__ unsigned short sW[64 * KP];
    const int tid = threadIdx.x;
    const int row0 = blockIdx.x * 64, col0 = blockIdx.y * 64;

    // stage A tile (f32 or bf16 -> bf16, fused affine+relu)
#pragma unroll
    for (int it = 0; it < (64 * K) / (256 * 4); ++it) {
        int idx = (it * 256 + tid) * 4;
        int r = idx / K, c = idx % K;
        int gr = row0 + r;
        float v0 = 0.f, v1 = 0.f, v2 = 0.f, v3 = 0.f;
        if (gr < nrows) {
            if (ABF16) {
                ushort4 u = *(const ushort4*)((const unsigned short*)Av + (size_t)gr * K + c);
                v0 = bf2f(u.x); v1 = bf2f(u.y); v2 = bf2f(u.z); v3 = bf2f(u.w);
            } else {
                float4 f = *(const float4*)((const float*)Av + (size_t)gr * K + c);
                v0 = f.x; v1 = f.y; v2 = f.z; v3 = f.w;
            }
            if (scale) {
                v0 = fmaxf(v0 * scale[c + 0] + shift[c + 0], 0.f);
                v1 = fmaxf(v1 * scale[c + 1] + shift[c + 1], 0.f);
                v2 = fmaxf(v2 * scale[c + 2] + shift[c + 2], 0.f);
                v3 = fmaxf(v3 * scale[c + 3] + shift[c + 3], 0.f);
            }
        }
        ushort4 o; o.x = f2bf(v0); o.y = f2bf(v1); o.z = f2bf(v2); o.w = f2bf(v3);
        *(ushort4*)(&sA[r * KP + c]) = o;
    }
    // stage W tile (already bf16)
#pragma unroll
    for (int it = 0; it < (64 * K) / (256 * 8); ++it) {
        int idx = (it * 256 + tid) * 8;
        int r = idx / K, c = idx % K;
        uint4 u = *(const uint4*)(Wt + (size_t)(col0 + r) * K + c);
        *(uint4*)(&sW[r * KP + c]) = u;
    }
    __syncthreads();

    const int w = tid >> 6, lane = tid & 63;
    const int wr = (w >> 1) * 32, wc = (w & 1) * 32;
    const int lr = lane & 15, kg = (lane >> 4) * 8;
    f32x4 acc[2][2] = {};
#pragma unroll
    for (int kk = 0; kk < K; kk += 32) {
        short8 af[2], bfr[2];
#pragma unroll
        for (int mi = 0; mi < 2; mi++)
            af[mi] = *(const short8*)(&sA[(wr + mi * 16 + lr) * KP + kk + kg]);
#pragma unroll
        for (int ni = 0; ni < 2; ni++)
            bfr[ni] = *(const short8*)(&sW[(wc + ni * 16 + lr) * KP + kk + kg]);
#pragma unroll
        for (int mi = 0; mi < 2; mi++)
#pragma unroll
            for (int ni = 0; ni < 2; ni++)
                acc[mi][ni] = __builtin_amdgcn_mfma_f32_16x16x32_bf16(af[mi], bfr[ni], acc[mi][ni], 0, 0, 0);
    }
    // epilogue: C[row][col], row=(lane>>4)*4+j, col=lane&15 within fragment
#pragma unroll
    for (int mi = 0; mi < 2; mi++) {
#pragma unroll
        for (int ni = 0; ni < 2; ni++) {
            int r = wr + mi * 16 + (lane >> 4) * 4;
            int cgl = col0 + wc + ni * 16 + (lane & 15);
            float bv = bias ? bias[cgl] : 0.f;
#pragma unroll
            for (int j = 0; j < 4; j++) {
                int gr = row0 + r + j;
                if (gr < nrows) {
                    float val = acc[mi][ni][j] + bv;
                    if (OBF16) ((unsigned short*)Cv)[(size_t)gr * Dout + cgl] = f2bf(val);
                    else       ((float*)Cv)[(size_t)gr * Dout + cgl] = val;
                }
            }
        }
    }
}

// ---------------- GCN aggregation: out[d] = dinv[d]*(sum_e dinv[s]*h[s] + dinv[d]*h[d]) + b ----------------
__global__ __launch_bounds__(256) void k_gcn_agg(const float* __restrict__ h,
        const int* __restrict__ roff, const int* __restrict__ srcs,
        const float* __restrict__ dinv, const float* __restrict__ b,
        float* __restrict__ out, int N) {
    int nw = (gridDim.x * 256) >> 6;
    int wid = (blockIdx.x * 256 + threadIdx.x) >> 6;
    int lane = threadIdx.x & 63;
    int c = lane * 2;
    float b0 = b[c], b1 = b[c + 1];
    for (int d = wid; d < N; d += nw) {
        float dv = dinv[d];
        float2 self = ((const float2*)(h + (size_t)d * 128))[lane];
        float ax = dv * self.x, ay = dv * self.y;
        int e0 = roff[d], e1 = roff[d + 1];
        for (int e = e0; e < e1; e++) {
            int s = srcs[e];
            float w = dinv[s];
            float2 v = ((const float2*)(h + (size_t)s * 128))[lane];
            ax += w * v.x; ay += w * v.y;
        }
        float2 o; o.x = dv * ax + b0; o.y = dv * ay + b1;
        ((float2*)(out + (size_t)d * 128))[lane] = o;
    }
}

// ---------------- GEN softmax aggregation (online), input affine+relu fused ----------------
// h2 = relu(t4*scale+shift); msg = h2[s]+eps; out[d] = softmax_agg + h2[d]
__global__ __launch_bounds__(256) void k_gen_agg(const float* __restrict__ t4,
        const int* __restrict__ roff, const int* __restrict__ srcs,
        const float* __restrict__ scale, const float* __restrict__ shift,
        float* __restrict__ out, int N) {
    int nw = (gridDim.x * 256) >> 6;
    int wid = (blockIdx.x * 256 + threadIdx.x) >> 6;
    int lane = threadIdx.x & 63;
    int c = lane * 2;
    float sc0 = scale[c], sc1 = scale[c + 1], sh0 = shift[c], sh1 = shift[c + 1];
    for (int d = wid; d < N; d += nw) {
        float mx0 = -1e30f, mx1 = -1e30f, de0 = 0.f, de1 = 0.f, nu0 = 0.f, nu1 = 0.f;
        int e0 = roff[d], e1 = roff[d + 1];
        for (int e = e0; e < e1; e++) {
            int s = srcs[e];
            float2 r = ((const float2*)(t4 + (size_t)s * 128))[lane];
            float v0 = fmaxf(r.x * sc0 + sh0, 0.f) + GEN_EPS;
            float v1 = fmaxf(r.y * sc1 + sh1, 0.f) + GEN_EPS;
            float nm0 = fmaxf(mx0, v0), nm1 = fmaxf(mx1, v1);
            float f0 = __expf(mx0 - nm0), f1 = __expf(mx1 - nm1);
            float w0 = __expf(v0 - nm0), w1 = __expf(v1 - nm1);
            de0 = de0 * f0 + w0; nu0 = nu0 * f0 + w0 * v0; mx0 = nm0;
            de1 = de1 * f1 + w1; nu1 = nu1 * f1 + w1 * v1; mx1 = nm1;
        }
        float2 rs = ((const float2*)(t4 + (size_t)d * 128))[lane];
        float h20 = fmaxf(rs.x * sc0 + sh0, 0.f);
        float h21 = fmaxf(rs.y * sc1 + sh1, 0.f);
        float a0 = (e1 > e0) ? nu0 / fmaxf(de0, 1e-16f) : 0.f;
        float a1 = (e1 > e0) ? nu1 / fmaxf(de1, 1e-16f) : 0.f;
        float2 o; o.x = a0 + h20; o.y = a1 + h21;
        ((float2*)(out + (size_t)d * 128))[lane] = o;
    }
}

// ---------------- BN column stats ----------------
template<typename T, int D>
__global__ __launch_bounds__(256) void k_stats(const T* __restrict__ h,
        float* __restrict__ gsum, float* __restrict__ gsq, int N) {
    constexpr int HC = D / 2, TPC = 256 / HC;
    int t = threadIdx.x;
    int cp = t % HC, slot = t / HC;
    int c = cp * 2;
    float s0 = 0.f, s1 = 0.f, q0 = 0.f, q1 = 0.f;
    for (int node = blockIdx.x * TPC + slot; node < N; node += gridDim.x * TPC) {
        float v0, v1;
        if (sizeof(T) == 2) {
            ushort2 u = *(const ushort2*)((const unsigned short*)h + (size_t)node * D + c);
            v0 = bf2f(u.x); v1 = bf2f(u.y);
        } else {
            float2 f = *(const float2*)((const float*)h + (size_t)node * D + c);
            v0 = f.x; v1 = f.y;
        }
        s0 += v0; s1 += v1; q0 += v0 * v0; q1 += v1 * v1;
    }
    __shared__ float red[256 * 4];
    red[t * 4] = s0; red[t * 4 + 1] = s1; red[t * 4 + 2] = q0; red[t * 4 + 3] = q1;
    __syncthreads();
    if (slot == 0) {
        for (int k2 = 1; k2 < TPC; k2++) {
            int o = (t + k2 * HC) * 4;
            s0 += red[o]; s1 += red[o + 1]; q0 += red[o + 2]; q1 += red[o + 3];
        }
        atomicAdd(&gsum[c], s0); atomicAdd(&gsum[c + 1], s1);
        atomicAdd(&gsq[c], q0); atomicAdd(&gsq[c + 1], q1);
    }
}

__global__ void k_fin(const float* __restrict__ sum, const float* __restrict__ sq,
        const float* __restrict__ g, const float* __restrict__ beta,
        float* __restrict__ scale, float* __restrict__ shift, int D, float invN) {
    int c = threadIdx.x;
    if (c < D) {
        float mu = sum[c] * invN;
        float var = sq[c] * invN - mu * mu;
        float s = g[c] * rsqrtf(var + BN_EPS);
        scale[c] = s;
        shift[c] = beta[c] - mu * s;
    }
}

// ---------------- log_softmax in place, wave per row of 64 ----------------
__global__ __launch_bounds__(256) void k_head(float* __restrict__ out, int N) {
    int wid = blockIdx.x * 4 + (threadIdx.x >> 6);
    int lane = threadIdx.x & 63;
    if (wid >= N) return;
    float v = out[(size_t)wid * 64 + lane];
    float m = v;
    for (int o = 32; o; o >>= 1) m = fmaxf(m, __shfl_xor(m, o));
    float e = __expf(v - m);
    float s = e;
    for (int o = 32; o; o >>= 1) s += __shfl_xor(s, o);
    out[(size_t)wid * 64 + lane] = v - m - __logf(s);
}

extern "C" void kernel_launch(void* const* d_in, const int* in_sizes, int n_in,
                              void* d_out, int out_size, void* d_ws, size_t ws_size,
                              hipStream_t stream) {
    const float* x   = (const float*)d_in[0];
    const float* W0  = (const float*)d_in[1];
    const float* b0  = (const float*)d_in[2];
    const float* g0  = (const float*)d_in[3];
    const float* be0 = (const float*)d_in[4];
    const float* W1  = (const float*)d_in[5];
    const float* b1  = (const float*)d_in[6];
    const float* g1  = (const float*)d_in[7];
    const float* be1 = (const float*)d_in[8];
    const float* Wg1 = (const float*)d_in[9];
    const float* bg1 = (const float*)d_in[10];
    const float* gg  = (const float*)d_in[11];
    const float* beg = (const float*)d_in[12];
    const float* Wg2 = (const float*)d_in[13];
    const float* bg2 = (const float*)d_in[14];
    const int*   ei  = (const int*)d_in[15];

    const int N = in_sizes[0] / DIN;
    const int E = in_sizes[15] / 2;
    const int* src = ei;
    const int* dst = ei + E;

    char* ws = (char*)d_ws;
    size_t off = 0;
    auto alloc = [&](size_t b) { size_t o = off; off = (off + b + 255) & ~(size_t)255; return o; };
    size_t o_counts = alloc((size_t)N * 4);
    size_t o_stats  = alloc(1024 * 4);
    size_t o_cursor = alloc((size_t)N * 4);
    size_t o_roff   = alloc(((size_t)N + 1) * 4);
    size_t o_srcs   = alloc((size_t)E * 4);
    size_t o_dinv   = alloc((size_t)N * 4);
    size_t o_ss     = alloc(1024 * 4);
    size_t o_w0t    = alloc(128 * 128 * 2);
    size_t o_w1t    = alloc(128 * 128 * 2);
    size_t o_wg1t   = alloc(256 * 128 * 2);
    size_t o_wg2t   = alloc(64 * 256 * 2);
    size_t o_xa     = alloc((size_t)N * 128 * 4);
    size_t o_xb     = alloc((size_t)N * 128 * 4);
    size_t o_c      = alloc((size_t)N * 256 * 2);
    (void)ws_size; (void)n_in; (void)out_size;

    int* counts = (int*)(ws + o_counts);
    float* stats = (float*)(ws + o_stats);
    int* cursor = (int*)(ws + o_cursor);
    int* roff = (int*)(ws + o_roff);
    int* srcs = (int*)(ws + o_srcs);
    float* dinv = (float*)(ws + o_dinv);
    float* ssz = (float*)(ws + o_ss);
    unsigned short* w0t  = (unsigned short*)(ws + o_w0t);
    unsigned short* w1t  = (unsigned short*)(ws + o_w1t);
    unsigned short* wg1t = (unsigned short*)(ws + o_wg1t);
    unsigned short* wg2t = (unsigned short*)(ws + o_wg2t);
    float* xa = (float*)(ws + o_xa);
    float* xb = (float*)(ws + o_xb);
    unsigned short* cb = (unsigned short*)(ws + o_c);

    float* sum0 = stats;       float* sq0 = stats + 128;
    float* sum1 = stats + 256; float* sq1 = stats + 384;
    float* sumg = stats + 512; float* sqg = stats + 768;
    float* scale0 = ssz;       float* shift0 = ssz + 128;
    float* scale1 = ssz + 256; float* shift1 = ssz + 384;
    float* scaleg = ssz + 512; float* shiftg = ssz + 768;

    // zero counts + stats (contiguous region)
    hipMemsetAsync(ws + o_counts, 0, o_cursor - o_counts, stream);

    // CSR build
    int egrid = (E + 255) / 256;
    k_hist<<<egrid, 256, 0, stream>>>(dst, counts, E);
    k_scan<<<1, 1024, 0, stream>>>(counts, roff, cursor, dinv, N);
    k_fill<<<egrid, 256, 0, stream>>>(src, dst, cursor, srcs, E);

    // weight transposes (bf16)
    k_wt<<<(128 * 128 + 255) / 256, 256, 0, stream>>>(W0, w0t, 128, 128);
    k_wt<<<(128 * 128 + 255) / 256, 256, 0, stream>>>(W1, w1t, 128, 128);
    k_wt<<<(128 * 256 + 255) / 256, 256, 0, stream>>>(Wg1, wg1t, 128, 256);
    k_wt<<<(256 * 64 + 255) / 256, 256, 0, stream>>>(Wg2, wg2t, 256, 64);

    int rb = (N + 63) / 64;
    const float invN = 1.f / (float)N;

    // layer 0: t0 = x@W0 -> xa ; agg -> xb(+b0); stats; finalize
    k_gemm<128, false, false><<<dim3(rb, 2), 256, 0, stream>>>(x, w0t, nullptr, nullptr, nullptr, xa, N, 128);
    k_gcn_agg<<<2048, 256, 0, stream>>>(xa, roff, srcs, dinv, b0, xb, N);
    k_stats<float, 128><<<1024, 256, 0, stream>>>(xb, sum0, sq0, N);
    k_fin<<<1, 256, 0, stream>>>(sum0, sq0, g0, be0, scale0, shift0, 128, invN);

    // layer 1: t3 = relu(bn(t1))@W1 -> xa ; agg -> xb(+b1); stats; finalize
    k_gemm<128, false, false><<<dim3(rb, 2), 256, 0, stream>>>(xb, w1t, nullptr, scale0, shift0, xa, N, 128);
    k_gcn_agg<<<2048, 256, 0, stream>>>(xa, roff, srcs, dinv, b1, xb, N);
    k_stats<float, 128><<<1024, 256, 0, stream>>>(xb, sum1, sq1, N);
    k_fin<<<1, 256, 0, stream>>>(sum1, sq1, g1, be1, scale1, shift1, 128, invN);

    // GEN conv: softmax-agg over relu(bn(t4)) + residual -> xa
    k_gen_agg<<<2048, 256, 0, stream>>>(xb, roff, srcs, scale1, shift1, xa, N);

    // MLP: t7 = t6@Wg1+bg1 -> cb (bf16); stats; finalize; t9 = relu(bn(t7))@Wg2+bg2 -> d_out
    k_gemm<128, false, true><<<dim3(rb, 4), 256, 0, stream>>>(xa, wg1t, bg1, nullptr, nullptr, cb, N, 256);
    k_stats<unsigned short, 256><<<1024, 256, 0, stream>>>(cb, sumg, sqg, N);
    k_fin<<<1, 256, 0, stream>>>(sumg, sqg, gg, beg, scaleg, shiftg, 256, invN);
    k_gemm<256, true, false><<<dim3(rb, 1), 256, 0, stream>>>(cb, wg2t, bg2, scaleg, shiftg, d_out, N, 64);

    // log_softmax in place
    k_head<<<(N + 3) / 4, 256, 0, stream>>>((float*)d_out, N);
}

// Round 2
// 617.378 us; speedup vs baseline: 1.2414x; 1.2414x over previous
//
#include <hip/hip_runtime.h>
#include <hip/hip_bf16.h>

#define DIN 128
#define DHID 128
#define DCLS 64
#define BN_EPS 1e-5f
#define GEN_EPS 1e-7f

typedef __attribute__((ext_vector_type(8))) short short8;
typedef __attribute__((ext_vector_type(4))) float f32x4;

static __device__ __forceinline__ float bf2f(unsigned short u) {
    union { float f; unsigned int i; } x; x.i = ((unsigned int)u) << 16; return x.f;
}
static __device__ __forceinline__ unsigned short f2bf(float f) {
    union { float f; unsigned int i; } x; x.f = f;
    unsigned int r = x.i + 0x7fffu + ((x.i >> 16) & 1u);
    return (unsigned short)(r >> 16);
}

// ---------------- CSR build ----------------
__global__ void k_hist(const int* __restrict__ dst, int* __restrict__ counts, int E) {
    int e = blockIdx.x * 256 + threadIdx.x;
    if (e < E) atomicAdd(&counts[dst[e]], 1);
}

// block-local exclusive prefix (1024 elems/block) -> roff(local), block totals -> bsum
__global__ __launch_bounds__(256) void k_scan1(const int* __restrict__ counts,
        int* __restrict__ roff, int* __restrict__ bsum, int N) {
    __shared__ int ls[256];
    int t = threadIdx.x;
    int base = blockIdx.x * 1024 + t * 4;
    int c0 = 0, c1 = 0, c2 = 0, c3 = 0;
    if (base + 3 < N) {
        int4 v = *(const int4*)(counts + base);
        c0 = v.x; c1 = v.y; c2 = v.z; c3 = v.w;
    } else {
        if (base + 0 < N) c0 = counts[base + 0];
        if (base + 1 < N) c1 = counts[base + 1];
        if (base + 2 < N) c2 = counts[base + 2];
        if (base + 3 < N) c3 = counts[base + 3];
    }
    ls[t] = c0 + c1 + c2 + c3;
    __syncthreads();
    for (int off = 1; off < 256; off <<= 1) {
        int v = (t >= off) ? ls[t - off] : 0;
        __syncthreads();
        ls[t] += v;
        __syncthreads();
    }
    int r = (t == 0) ? 0 : ls[t - 1];
    if (base + 0 < N) { roff[base + 0] = r; r += c0; }
    if (base + 1 < N) { roff[base + 1] = r; r += c1; }
    if (base + 2 < N) { roff[base + 2] = r; r += c2; }
    if (base + 3 < N) { roff[base + 3] = r; }
    if (t == 255) bsum[blockIdx.x] = ls[255];
}

// exclusive scan of block sums in place (nblk <= 1024)
__global__ __launch_bounds__(1024) void k_scan2(int* __restrict__ bsum, int nblk) {
    __shared__ int ls[1024];
    int t = threadIdx.x;
    ls[t] = (t < nblk) ? bsum[t] : 0;
    __syncthreads();
    for (int off = 1; off < 1024; off <<= 1) {
        int v = (t >= off) ? ls[t - off] : 0;
        __syncthreads();
        ls[t] += v;
        __syncthreads();
    }
    if (t < nblk) bsum[t] = (t == 0) ? 0 : ls[t - 1];
}

// add block base, fill cursor + dinv + roff[N]
__global__ void k_scan3(const int* __restrict__ counts, const int* __restrict__ bsum,
        int* __restrict__ roff, int* __restrict__ cursor, float* __restrict__ dinv,
        int N, int E) {
    int i = blockIdx.x * 256 + threadIdx.x;
    if (i < N) {
        int r = roff[i] + bsum[i >> 10];
        roff[i] = r; cursor[i] = r;
        dinv[i] = rsqrtf((float)(counts[i] + 1));
    }
    if (i == 0) roff[N] = E;
}

__global__ void k_fill(const int* __restrict__ src, const int* __restrict__ dst,
        int* __restrict__ cursor, int* __restrict__ srcs, int E) {
    int e = blockIdx.x * 256 + threadIdx.x;
    if (e < E) {
        int d = dst[e];
        int p = atomicAdd(&cursor[d], 1);
        srcs[p] = src[e];
    }
}

// ---------------- weight transpose to bf16: Wt[n][k] = W[k][n] ----------------
__global__ void k_wt(const float* __restrict__ W, unsigned short* __restrict__ Wt, int K, int Dout) {
    int i = blockIdx.x * 256 + threadIdx.x;
    if (i >= K * Dout) return;
    int n = i / K, k = i - n * K;
    Wt[i] = f2bf(W[(size_t)k * Dout + n]);
}

// ---------------- GEMM: C[nrows,Dout] = op(A)[nrows,K] @ W[K,Dout] (+bias) ----------------
// op(A) = relu(A*scale+shift) if scale!=null.  Wt is bf16 row-major [Dout][K].
template<int K, bool ABF16, bool OBF16>
__global__ __launch_bounds__(256) void k_gemm(const void* __restrict__ Av,
        const unsigned short* __restrict__ Wt, const float* __restrict__ bias,
        const float* __restrict__ scale, const float* __restrict__ shift,
        void* __restrict__ Cv, int nrows, int Dout) {
    constexpr int KP = K + 8;
    __shared__ unsigned short sA[64 * KP];
    __shared__ unsigned short sW[64 * KP];
    const int tid = threadIdx.x;
    const int row0 = blockIdx.x * 64, col0 = blockIdx.y * 64;

    // stage A tile (f32 or bf16 -> bf16, fused affine+relu)
#pragma unroll
    for (int it = 0; it < (64 * K) / (256 * 4); ++it) {
        int idx = (it * 256 + tid) * 4;
        int r = idx / K, c = idx % K;
        int gr = row0 + r;
        float v0 = 0.f, v1 = 0.f, v2 = 0.f, v3 = 0.f;
        if (gr < nrows) {
            if (ABF16) {
                ushort4 u = *(const ushort4*)((const unsigned short*)Av + (size_t)gr * K + c);
                v0 = bf2f(u.x); v1 = bf2f(u.y); v2 = bf2f(u.z); v3 = bf2f(u.w);
            } else {
                float4 f = *(const float4*)((const float*)Av + (size_t)gr * K + c);
                v0 = f.x; v1 = f.y; v2 = f.z; v3 = f.w;
            }
            if (scale) {
                v0 = fmaxf(v0 * scale[c + 0] + shift[c + 0], 0.f);
                v1 = fmaxf(v1 * scale[c + 1] + shift[c + 1], 0.f);
                v2 = fmaxf(v2 * scale[c + 2] + shift[c + 2], 0.f);
                v3 = fmaxf(v3 * scale[c + 3] + shift[c + 3], 0.f);
            }
        }
        ushort4 o; o.x = f2bf(v0); o.y = f2bf(v1); o.z = f2bf(v2); o.w = f2bf(v3);
        *(ushort4*)(&sA[r * KP + c]) = o;
    }
    // stage W tile (already bf16)
#pragma unroll
    for (int it = 0; it < (64 * K) / (256 * 8); ++it) {
        int idx = (it * 256 + tid) * 8;
        int r = idx / K, c = idx % K;
        uint4 u = *(const uint4*)(Wt + (size_t)(col0 + r) * K + c);
        *(uint4*)(&sW[r * KP + c]) = u;
    }
    __syncthreads();

    const int w = tid >> 6, lane = tid & 63;
    const int wr = (w >> 1) * 32, wc = (w & 1) * 32;
    const int lr = lane & 15, kg = (lane >> 4) * 8;
    f32x4 acc[2][2] = {};
#pragma unroll
    for (int kk = 0; kk < K; kk += 32) {
        short8 af[2], bfr[2];
#pragma unroll
        for (int mi = 0; mi < 2; mi++)
            af[mi] = *(const short8*)(&sA[(wr + mi * 16 + lr) * KP + kk + kg]);
#pragma unroll
        for (int ni = 0; ni < 2; ni++)
            bfr[ni] = *(const short8*)(&sW[(wc + ni * 16 + lr) * KP + kk + kg]);
#pragma unroll
        for (int mi = 0; mi < 2; mi++)
#pragma unroll
            for (int ni = 0; ni < 2; ni++)
                acc[mi][ni] = __builtin_amdgcn_mfma_f32_16x16x32_bf16(af[mi], bfr[ni], acc[mi][ni], 0, 0, 0);
    }
    // epilogue: C[row][col], row=(lane>>4)*4+j, col=lane&15 within fragment
#pragma unroll
    for (int mi = 0; mi < 2; mi++) {
#pragma unroll
        for (int ni = 0; ni < 2; ni++) {
            int r = wr + mi * 16 + (lane >> 4) * 4;
            int cgl = col0 + wc + ni * 16 + (lane & 15);
            float bv = bias ? bias[cgl] : 0.f;
#pragma unroll
            for (int j = 0; j < 4; j++) {
                int gr = row0 + r + j;
                if (gr < nrows) {
                    float val = acc[mi][ni][j] + bv;
                    if (OBF16) ((unsigned short*)Cv)[(size_t)gr * Dout + cgl] = f2bf(val);
                    else       ((float*)Cv)[(size_t)gr * Dout + cgl] = val;
                }
            }
        }
    }
}

// ---------------- GCN aggregation (bf16 features): out[d] = dinv[d]*(sum dinv[s]*h[s] + dinv[d]*h[d]) + b
__global__ __launch_bounds__(256) void k_gcn_agg(const unsigned short* __restrict__ h,
        const int* __restrict__ roff, const int* __restrict__ srcs,
        const float* __restrict__ dinv, const float* __restrict__ b,
        unsigned short* __restrict__ out, int N) {
    int nw = (gridDim.x * 256) >> 6;
    int wid = (blockIdx.x * 256 + threadIdx.x) >> 6;
    int lane = threadIdx.x & 63;
    int c = lane * 2;
    float b0 = b[c], b1 = b[c + 1];
    for (int d = wid; d < N; d += nw) {
        float dv = dinv[d];
        ushort2 su = ((const ushort2*)(h + (size_t)d * 128))[lane];
        float ax = dv * bf2f(su.x), ay = dv * bf2f(su.y);
        int e0 = roff[d], e1 = roff[d + 1];
        for (int e = e0; e < e1; e++) {
            int s = srcs[e];
            float w = dinv[s];
            ushort2 v = ((const ushort2*)(h + (size_t)s * 128))[lane];
            ax += w * bf2f(v.x); ay += w * bf2f(v.y);
        }
        ushort2 o; o.x = f2bf(dv * ax + b0); o.y = f2bf(dv * ay + b1);
        ((ushort2*)(out + (size_t)d * 128))[lane] = o;
    }
}

// ---------------- GEN softmax aggregation (online, bf16 features), affine+relu fused
__global__ __launch_bounds__(256) void k_gen_agg(const unsigned short* __restrict__ t4,
        const int* __restrict__ roff, const int* __restrict__ srcs,
        const float* __restrict__ scale, const float* __restrict__ shift,
        unsigned short* __restrict__ out, int N) {
    int nw = (gridDim.x * 256) >> 6;
    int wid = (blockIdx.x * 256 + threadIdx.x) >> 6;
    int lane = threadIdx.x & 63;
    int c = lane * 2;
    float sc0 = scale[c], sc1 = scale[c + 1], sh0 = shift[c], sh1 = shift[c + 1];
    for (int d = wid; d < N; d += nw) {
        float mx0 = -1e30f, mx1 = -1e30f, de0 = 0.f, de1 = 0.f, nu0 = 0.f, nu1 = 0.f;
        int e0 = roff[d], e1 = roff[d + 1];
        for (int e = e0; e < e1; e++) {
            int s = srcs[e];
            ushort2 r = ((const ushort2*)(t4 + (size_t)s * 128))[lane];
            float v0 = fmaxf(bf2f(r.x) * sc0 + sh0, 0.f) + GEN_EPS;
            float v1 = fmaxf(bf2f(r.y) * sc1 + sh1, 0.f) + GEN_EPS;
            float nm0 = fmaxf(mx0, v0), nm1 = fmaxf(mx1, v1);
            float f0 = __expf(mx0 - nm0), f1 = __expf(mx1 - nm1);
            float w0 = __expf(v0 - nm0), w1 = __expf(v1 - nm1);
            de0 = de0 * f0 + w0; nu0 = nu0 * f0 + w0 * v0; mx0 = nm0;
            de1 = de1 * f1 + w1; nu1 = nu1 * f1 + w1 * v1; mx1 = nm1;
        }
        ushort2 rs = ((const ushort2*)(t4 + (size_t)d * 128))[lane];
        float h20 = fmaxf(bf2f(rs.x) * sc0 + sh0, 0.f);
        float h21 = fmaxf(bf2f(rs.y) * sc1 + sh1, 0.f);
        float a0 = (e1 > e0) ? nu0 / fmaxf(de0, 1e-16f) : 0.f;
        float a1 = (e1 > e0) ? nu1 / fmaxf(de1, 1e-16f) : 0.f;
        ushort2 o; o.x = f2bf(a0 + h20); o.y = f2bf(a1 + h21);
        ((ushort2*)(out + (size_t)d * 128))[lane] = o;
    }
}

// ---------------- BN column stats ----------------
template<int D>
__global__ __launch_bounds__(256) void k_stats(const unsigned short* __restrict__ h,
        float* __restrict__ gsum, float* __restrict__ gsq, int N) {
    constexpr int HC = D / 2, TPC = 256 / HC;
    int t = threadIdx.x;
    int cp = t % HC, slot = t / HC;
    int c = cp * 2;
    float s0 = 0.f, s1 = 0.f, q0 = 0.f, q1 = 0.f;
    for (int node = blockIdx.x * TPC + slot; node < N; node += gridDim.x * TPC) {
        ushort2 u = *(const ushort2*)(h + (size_t)node * D + c);
        float v0 = bf2f(u.x), v1 = bf2f(u.y);
        s0 += v0; s1 += v1; q0 += v0 * v0; q1 += v1 * v1;
    }
    __shared__ float red[256 * 4];
    red[t * 4] = s0; red[t * 4 + 1] = s1; red[t * 4 + 2] = q0; red[t * 4 + 3] = q1;
    __syncthreads();
    if (slot == 0) {
        for (int k2 = 1; k2 < TPC; k2++) {
            int o = (t + k2 * HC) * 4;
            s0 += red[o]; s1 += red[o + 1]; q0 += red[o + 2]; q1 += red[o + 3];
        }
        atomicAdd(&gsum[c], s0); atomicAdd(&gsum[c + 1], s1);
        atomicAdd(&gsq[c], q0); atomicAdd(&gsq[c + 1], q1);
    }
}

__global__ void k_fin(const float* __restrict__ sum, const float* __restrict__ sq,
        const float* __restrict__ g, const float* __restrict__ beta,
        float* __restrict__ scale, float* __restrict__ shift, int D, float invN) {
    int c = threadIdx.x;
    if (c < D) {
        float mu = sum[c] * invN;
        float var = sq[c] * invN - mu * mu;
        float s = g[c] * rsqrtf(var + BN_EPS);
        scale[c] = s;
        shift[c] = beta[c] - mu * s;
    }
}

// ---------------- log_softmax in place, wave per row of 64 ----------------
__global__ __launch_bounds__(256) void k_head(float* __restrict__ out, int N) {
    int wid = blockIdx.x * 4 + (threadIdx.x >> 6);
    int lane = threadIdx.x & 63;
    if (wid >= N) return;
    float v = out[(size_t)wid * 64 + lane];
    float m = v;
    for (int o = 32; o; o >>= 1) m = fmaxf(m, __shfl_xor(m, o));
    float e = __expf(v - m);
    float s = e;
    for (int o = 32; o; o >>= 1) s += __shfl_xor(s, o);
    out[(size_t)wid * 64 + lane] = v - m - __logf(s);
}

extern "C" void kernel_launch(void* const* d_in, const int* in_sizes, int n_in,
                              void* d_out, int out_size, void* d_ws, size_t ws_size,
                              hipStream_t stream) {
    const float* x   = (const float*)d_in[0];
    const float* W0  = (const float*)d_in[1];
    const float* b0  = (const float*)d_in[2];
    const float* g0  = (const float*)d_in[3];
    const float* be0 = (const float*)d_in[4];
    const float* W1  = (const float*)d_in[5];
    const float* b1  = (const float*)d_in[6];
    const float* g1  = (const float*)d_in[7];
    const float* be1 = (const float*)d_in[8];
    const float* Wg1 = (const float*)d_in[9];
    const float* bg1 = (const float*)d_in[10];
    const float* gg  = (const float*)d_in[11];
    const float* beg = (const float*)d_in[12];
    const float* Wg2 = (const float*)d_in[13];
    const float* bg2 = (const float*)d_in[14];
    const int*   ei  = (const int*)d_in[15];

    const int N = in_sizes[0] / DIN;
    const int E = in_sizes[15] / 2;
    const int* src = ei;
    const int* dst = ei + E;

    char* ws = (char*)d_ws;
    size_t off = 0;
    auto alloc = [&](size_t b) { size_t o = off; off = (off + b + 255) & ~(size_t)255; return o; };
    size_t o_counts = alloc((size_t)N * 4);
    size_t o_stats  = alloc(1024 * 4);
    size_t o_cursor = alloc((size_t)N * 4);
    size_t o_roff   = alloc(((size_t)N + 1) * 4);
    size_t o_srcs   = alloc((size_t)E * 4);
    size_t o_dinv   = alloc((size_t)N * 4);
    size_t o_bsum   = alloc(1024 * 4);
    size_t o_ss     = alloc(1024 * 4);
    size_t o_w0t    = alloc(128 * 128 * 2);
    size_t o_w1t    = alloc(128 * 128 * 2);
    size_t o_wg1t   = alloc(256 * 128 * 2);
    size_t o_wg2t   = alloc(64 * 256 * 2);
    size_t o_xa     = alloc((size_t)N * 128 * 2);
    size_t o_xb     = alloc((size_t)N * 128 * 2);
    size_t o_c      = alloc((size_t)N * 256 * 2);
    (void)ws_size; (void)n_in; (void)out_size;

    int* counts = (int*)(ws + o_counts);
    float* stats = (float*)(ws + o_stats);
    int* cursor = (int*)(ws + o_cursor);
    int* roff = (int*)(ws + o_roff);
    int* srcs = (int*)(ws + o_srcs);
    float* dinv = (float*)(ws + o_dinv);
    int* bsum = (int*)(ws + o_bsum);
    float* ssz = (float*)(ws + o_ss);
    unsigned short* w0t  = (unsigned short*)(ws + o_w0t);
    unsigned short* w1t  = (unsigned short*)(ws + o_w1t);
    unsigned short* wg1t = (unsigned short*)(ws + o_wg1t);
    unsigned short* wg2t = (unsigned short*)(ws + o_wg2t);
    unsigned short* xa = (unsigned short*)(ws + o_xa);
    unsigned short* xb = (unsigned short*)(ws + o_xb);
    unsigned short* cb = (unsigned short*)(ws + o_c);

    float* sum0 = stats;       float* sq0 = stats + 128;
    float* sum1 = stats + 256; float* sq1 = stats + 384;
    float* sumg = stats + 512; float* sqg = stats + 768;
    float* scale0 = ssz;       float* shift0 = ssz + 128;
    float* scale1 = ssz + 256; float* shift1 = ssz + 384;
    float* scaleg = ssz + 512; float* shiftg = ssz + 768;

    // zero counts + stats (contiguous region)
    hipMemsetAsync(ws + o_counts, 0, o_cursor - o_counts, stream);

    // CSR build (hierarchical scan)
    int egrid = (E + 255) / 256;
    int nblk = (N + 1023) / 1024;
    k_hist<<<egrid, 256, 0, stream>>>(dst, counts, E);
    k_scan1<<<nblk, 256, 0, stream>>>(counts, roff, bsum, N);
    k_scan2<<<1, 1024, 0, stream>>>(bsum, nblk);
    k_scan3<<<(N + 255) / 256, 256, 0, stream>>>(counts, bsum, roff, cursor, dinv, N, E);
    k_fill<<<egrid, 256, 0, stream>>>(src, dst, cursor, srcs, E);

    // weight transposes (bf16)
    k_wt<<<(128 * 128 + 255) / 256, 256, 0, stream>>>(W0, w0t, 128, 128);
    k_wt<<<(128 * 128 + 255) / 256, 256, 0, stream>>>(W1, w1t, 128, 128);
    k_wt<<<(128 * 256 + 255) / 256, 256, 0, stream>>>(Wg1, wg1t, 128, 256);
    k_wt<<<(256 * 64 + 255) / 256, 256, 0, stream>>>(Wg2, wg2t, 256, 64);

    int rb = (N + 63) / 64;
    const float invN = 1.f / (float)N;

    // layer 0: t0 = x@W0 -> xa(bf16) ; agg -> xb(+b0); stats; finalize
    k_gemm<128, false, true><<<dim3(rb, 2), 256, 0, stream>>>(x, w0t, nullptr, nullptr, nullptr, xa, N, 128);
    k_gcn_agg<<<2048, 256, 0, stream>>>(xa, roff, srcs, dinv, b0, xb, N);
    k_stats<128><<<1024, 256, 0, stream>>>(xb, sum0, sq0, N);
    k_fin<<<1, 256, 0, stream>>>(sum0, sq0, g0, be0, scale0, shift0, 128, invN);

    // layer 1: t3 = relu(bn(t1))@W1 -> xa ; agg -> xb(+b1); stats; finalize
    k_gemm<128, true, true><<<dim3(rb, 2), 256, 0, stream>>>(xb, w1t, nullptr, scale0, shift0, xa, N, 128);
    k_gcn_agg<<<2048, 256, 0, stream>>>(xa, roff, srcs, dinv, b1, xb, N);
    k_stats<128><<<1024, 256, 0, stream>>>(xb, sum1, sq1, N);
    k_fin<<<1, 256, 0, stream>>>(sum1, sq1, g1, be1, scale1, shift1, 128, invN);

    // GEN conv: softmax-agg over relu(bn(t4)) + residual -> xa (bf16)
    k_gen_agg<<<2048, 256, 0, stream>>>(xb, roff, srcs, scale1, shift1, xa, N);

    // MLP: t7 = t6@Wg1+bg1 -> cb (bf16); stats; finalize; t9 = relu(bn(t7))@Wg2+bg2 -> d_out
    k_gemm<128, true, true><<<dim3(rb, 4), 256, 0, stream>>>(xa, wg1t, bg1, nullptr, nullptr, cb, N, 256);
    k_stats<256><<<1024, 256, 0, stream>>>(cb, sumg, sqg, N);
    k_fin<<<1, 256, 0, stream>>>(sumg, sqg, gg, beg, scaleg, shiftg, 256, invN);
    k_gemm<256, true, false><<<dim3(rb, 1), 256, 0, stream>>>(cb, wg2t, bg2, scaleg, shiftg, d_out, N, 64);

    // log_softmax in place
    k_head<<<(N + 3) / 4, 256, 0, stream>>>((float*)d_out, N);
}